// Round 3
// baseline (180.703 us; speedup 1.0000x reference)
//
#include <hip/hip_runtime.h>
#include <math.h>

// Problem constants: B=4, S=2048, DIN=1024, DOUT=1024, E=16, K=2
#define DIN_  1024
#define DOUT_ 1024
#define NE    16
#define KK    2
#define NTOK  8192
#define TPB   16          // tokens per block

// ws layout: [0,128KB): float wc[E][K][DIN] compact expert columns

// ---------------------------------------------------------------------------
// Kernel A: compact expert_w columns j=0,1 into Wc[e][j][d]. 128 KB.
// ---------------------------------------------------------------------------
__global__ __launch_bounds__(256) void compact_w_kernel(
    const float* __restrict__ ew,   // [E, DIN, DOUT]
    float* __restrict__ wc)         // [E, K, DIN]
{
    int i = blockIdx.x * 256 + threadIdx.x;   // over NE*KK*DIN = 32768
    if (i >= NE * KK * DIN_) return;
    int d = i & (DIN_ - 1);
    int j = (i >> 10) & 1;
    int e = i >> 11;
    wc[i] = ew[(size_t)e * DIN_ * DOUT_ + (size_t)d * DOUT_ + j];
}

// ---------------------------------------------------------------------------
// Fused kernel: gating + top-2 + expert dots + broadcast store.
// Block = 256 threads = 16 tokens x 16 d-segments (64 d each).
// x is loaded ONCE into registers (16 float4/thread) and reused for the
// expert dot phase. All global loads/stores coalesced.
// ---------------------------------------------------------------------------
__global__ __launch_bounds__(256) void moe_fused_kernel(
    const float* __restrict__ x,        // [NTOK, DIN]
    const float* __restrict__ gate_w,   // [DIN, E]
    const float* __restrict__ gate_b,   // [E]
    const float* __restrict__ ebias,    // [E]
    const float* __restrict__ wc,       // [E, K, DIN]
    const float* __restrict__ expert_b, // [E, DOUT]
    float* __restrict__ out_final,      // [NTOK, DOUT]
    float* __restrict__ out_probs,      // [NTOK, E]
    float* __restrict__ out_idx,        // [NTOK, K] as float
    int write_aux)
{
    __shared__ float red[NE][16][17];   // [e][seg][tok+pad]  ~17.4 KB
    __shared__ float lgt[TPB * NE];     // [tok][e]
    __shared__ float4 s_rec[TPB];       // (e0, e1, w0, w1)
    __shared__ float s_final[TPB];

    const int tid = threadIdx.x;
    const int seg = tid >> 4;           // 0..15
    const int tok = tid & 15;           // 0..15
    const int token = blockIdx.x * TPB + tok;

    // ---- load my 64 x-values into registers (kept for both phases) -------
    const float4* x4 = (const float4*)(x + (size_t)token * DIN_) + seg * 16;
    float4 xr[16];
#pragma unroll
    for (int i = 0; i < 16; i++) xr[i] = x4[i];

    // ---- Phase 1: gating partials, all 16 experts over my 64 d's ---------
    const float4* gw4 = (const float4*)gate_w;  // row d = 4 float4s
    float acc[NE];
#pragma unroll
    for (int e = 0; e < NE; e++) acc[e] = 0.f;

#pragma unroll 4
    for (int i = 0; i < 16; i++) {
        float4 xv = xr[i];
        int d0 = seg * 64 + i * 4;
#pragma unroll
        for (int j = 0; j < 4; j++) {
            int d = d0 + j;
            float xs = (j == 0) ? xv.x : (j == 1) ? xv.y : (j == 2) ? xv.z : xv.w;
            float4 g0 = gw4[d * 4 + 0];
            float4 g1 = gw4[d * 4 + 1];
            float4 g2 = gw4[d * 4 + 2];
            float4 g3 = gw4[d * 4 + 3];
            acc[0]  += xs * g0.x; acc[1]  += xs * g0.y; acc[2]  += xs * g0.z; acc[3]  += xs * g0.w;
            acc[4]  += xs * g1.x; acc[5]  += xs * g1.y; acc[6]  += xs * g1.z; acc[7]  += xs * g1.w;
            acc[8]  += xs * g2.x; acc[9]  += xs * g2.y; acc[10] += xs * g2.z; acc[11] += xs * g2.w;
            acc[12] += xs * g3.x; acc[13] += xs * g3.y; acc[14] += xs * g3.z; acc[15] += xs * g3.w;
        }
    }
#pragma unroll
    for (int e = 0; e < NE; e++) red[e][seg][tok] = acc[e];
    __syncthreads();

    // ---- Phase 2: reduce over segs, sigmoid, write probs (coalesced) -----
    {
        const int rtok = tid >> 4;
        const int e    = tid & 15;
        float s = 0.f;
#pragma unroll
        for (int sg = 0; sg < 16; sg++) s += red[e][sg][rtok];
        s += gate_b[e];
        if (write_aux) {
            float prob = 1.f / (1.f + expf(-s));
            out_probs[(size_t)(blockIdx.x * TPB + rtok) * NE + e] = prob;
        }
        lgt[rtok * NE + e] = s;
    }
    __syncthreads();

    // ---- Phase 3: top-2 per token (threads 0..15) ------------------------
    if (tid < TPB) {
        const int ftok = tid;
        const int gtoken = blockIdx.x * TPB + ftok;
        float go[NE], logit[NE];
#pragma unroll
        for (int e = 0; e < NE; e++) {
            go[e] = lgt[ftok * NE + e];
            logit[e] = go[e] + ebias[e];
        }
        int i0 = 0;
        for (int e = 1; e < NE; e++) if (logit[e] > logit[i0]) i0 = e;
        int i1 = -1;
        for (int e = 0; e < NE; e++) {
            if (e == i0) continue;
            if (i1 < 0 || logit[e] > logit[i1]) i1 = e;
        }
        float p0 = 1.f / (1.f + expf(-go[i0]));
        float p1 = 1.f / (1.f + expf(-go[i1]));
        float inv = 1.f / (p0 + p1);
        if (write_aux) {
            out_idx[(size_t)gtoken * KK + 0] = (float)i0;
            out_idx[(size_t)gtoken * KK + 1] = (float)i1;
        }
        s_rec[ftok] = make_float4((float)i0, (float)i1, p0 * inv, p1 * inv);
    }
    __syncthreads();

    // ---- Phase 4: expert dots from registers + wc (L2-hot) ---------------
    {
        float4 rec = s_rec[tok];
        int e0 = (int)rec.x;
        int e1 = (int)rec.y;
        const float4* w0 = (const float4*)(wc + ((size_t)e0 * KK + 0) * DIN_) + seg * 16;
        const float4* w1 = (const float4*)(wc + ((size_t)e1 * KK + 1) * DIN_) + seg * 16;
        float g0 = 0.f, g1 = 0.f;
#pragma unroll 4
        for (int i = 0; i < 16; i++) {
            float4 xv = xr[i];
            float4 a = w0[i];
            float4 b = w1[i];
            g0 += xv.x * a.x + xv.y * a.y + xv.z * a.z + xv.w * a.w;
            g1 += xv.x * b.x + xv.y * b.y + xv.z * b.z + xv.w * b.w;
        }
        red[0][seg][tok] = g0;
        red[1][seg][tok] = g1;
    }
    __syncthreads();

    // ---- Phase 5: finalize scalar per token ------------------------------
    if (tid < TPB) {
        const int ftok = tid;
        float4 rec = s_rec[ftok];
        int e0 = (int)rec.x;
        int e1 = (int)rec.y;
        float g0 = 0.f, g1 = 0.f;
#pragma unroll
        for (int sg = 0; sg < 16; sg++) { g0 += red[0][sg][ftok]; g1 += red[1][sg][ftok]; }
        g0 += expert_b[(size_t)e0 * DOUT_ + 0];
        g1 += expert_b[(size_t)e1 * DOUT_ + 1];
        s_final[ftok] = rec.z * g0 + rec.w * g1;
    }
    __syncthreads();

    // ---- Phase 6: broadcast stores, fully coalesced ----------------------
    // iter k: all 256 threads write token k's row (256 float4 = 4 KB)
    float4* ob = (float4*)(out_final + (size_t)blockIdx.x * TPB * DOUT_);
#pragma unroll 4
    for (int k = 0; k < TPB; k++) {
        float f = s_final[k];
        ob[k * (DOUT_ / 4) + tid] = make_float4(f, f, f, f);
    }
}

// ---------------------------------------------------------------------------
extern "C" void kernel_launch(void* const* d_in, const int* in_sizes, int n_in,
                              void* d_out, int out_size, void* d_ws, size_t ws_size,
                              hipStream_t stream) {
    const float* x        = (const float*)d_in[0];
    const float* gate_w   = (const float*)d_in[1];
    const float* gate_b   = (const float*)d_in[2];
    const float* expert_w = (const float*)d_in[3];
    const float* expert_b = (const float*)d_in[4];
    const float* ebias    = (const float*)d_in[5];
    float* out = (float*)d_out;

    float* wc = (float*)d_ws;   // 128 KB compact expert columns

    float* out_final = out;
    float* out_probs = out + (size_t)NTOK * DOUT_;
    float* out_idx   = out_probs + (size_t)NTOK * NE;
    int write_aux = (out_size >= NTOK * DOUT_ + NTOK * NE + NTOK * KK) ? 1 : 0;

    compact_w_kernel<<<(NE * KK * DIN_ + 255) / 256, 256, 0, stream>>>(expert_w, wc);
    moe_fused_kernel<<<NTOK / TPB, 256, 0, stream>>>(
        x, gate_w, gate_b, ebias, wc, expert_b,
        out_final, out_probs, out_idx, write_aux);
}

// Round 4
// 157.433 us; speedup vs baseline: 1.1478x; 1.1478x over previous
//
#include <hip/hip_runtime.h>
#include <math.h>

// Problem constants: B=4, S=2048, DIN=1024, DOUT=1024, E=16, K=2
#define DIN_  1024
#define DOUT_ 1024
#define NE    16
#define KK    2
#define NTOK  8192
#define TPB   16          // tokens per block

// ws layout: [0,128KB): float wc[E][K][DIN] compact expert columns

// ---------------------------------------------------------------------------
// Kernel A: compact expert_w columns j=0,1 into Wc[e][j][d]. 128 KB.
// ---------------------------------------------------------------------------
__global__ __launch_bounds__(256) void compact_w_kernel(
    const float* __restrict__ ew,   // [E, DIN, DOUT]
    float* __restrict__ wc)         // [E, K, DIN]
{
    int i = blockIdx.x * 256 + threadIdx.x;   // over NE*KK*DIN = 32768
    if (i >= NE * KK * DIN_) return;
    int d = i & (DIN_ - 1);
    int j = (i >> 10) & 1;
    int e = i >> 11;
    wc[i] = ew[(size_t)e * DIN_ * DOUT_ + (size_t)d * DOUT_ + j];
}

// ---------------------------------------------------------------------------
// Fused kernel: gating + top-2 + expert dots + broadcast store.
// Block = 256 threads = 16 tokens x 16 d-segments (64 d each).
// x is loaded ONCE into registers (16 float4/thread, FULLY UNROLLED so it
// never spills) and reused for the expert dot phase.
// ---------------------------------------------------------------------------
__global__ __launch_bounds__(256) void moe_fused_kernel(
    const float* __restrict__ x,        // [NTOK, DIN]
    const float* __restrict__ gate_w,   // [DIN, E]
    const float* __restrict__ gate_b,   // [E]
    const float* __restrict__ ebias,    // [E]
    const float* __restrict__ wc,       // [E, K, DIN]
    const float* __restrict__ expert_b, // [E, DOUT]
    float* __restrict__ out_final,      // [NTOK, DOUT]
    float* __restrict__ out_probs,      // [NTOK, E]
    float* __restrict__ out_idx,        // [NTOK, K] as float
    int write_aux)
{
    // red[seg][tok][e(+pad)] : phase-1 scatter and phase-2 gather both <=2-way
    __shared__ float red[16][16][17];   // 17.4 KB
    __shared__ float lgt[TPB * NE];     // [tok][e]
    __shared__ float4 s_rec[TPB];       // (e0, e1, w0, w1)
    __shared__ float s_final[TPB];

    const int tid = threadIdx.x;
    const int seg = tid >> 4;           // 0..15
    const int tok = tid & 15;           // 0..15
    const int token = blockIdx.x * TPB + tok;

    // ---- load my 64 x-values into registers (kept for both phases) -------
    const float4* x4 = (const float4*)(x + (size_t)token * DIN_) + seg * 16;
    float4 xr[16];
#pragma unroll
    for (int i = 0; i < 16; i++) xr[i] = x4[i];

    // ---- Phase 1: gating partials, all 16 experts over my 64 d's ---------
    const float4* gw4 = (const float4*)gate_w;  // row d = 4 float4s
    float acc[NE];
#pragma unroll
    for (int e = 0; e < NE; e++) acc[e] = 0.f;

#pragma unroll
    for (int i = 0; i < 16; i++) {
        float4 xv = xr[i];
        int d0 = seg * 64 + i * 4;
#pragma unroll
        for (int j = 0; j < 4; j++) {
            int d = d0 + j;
            float xs = (j == 0) ? xv.x : (j == 1) ? xv.y : (j == 2) ? xv.z : xv.w;
            float4 g0 = gw4[d * 4 + 0];
            float4 g1 = gw4[d * 4 + 1];
            float4 g2 = gw4[d * 4 + 2];
            float4 g3 = gw4[d * 4 + 3];
            acc[0]  += xs * g0.x; acc[1]  += xs * g0.y; acc[2]  += xs * g0.z; acc[3]  += xs * g0.w;
            acc[4]  += xs * g1.x; acc[5]  += xs * g1.y; acc[6]  += xs * g1.z; acc[7]  += xs * g1.w;
            acc[8]  += xs * g2.x; acc[9]  += xs * g2.y; acc[10] += xs * g2.z; acc[11] += xs * g2.w;
            acc[12] += xs * g3.x; acc[13] += xs * g3.y; acc[14] += xs * g3.z; acc[15] += xs * g3.w;
        }
    }
#pragma unroll
    for (int e = 0; e < NE; e++) red[seg][tok][e] = acc[e];
    __syncthreads();

    // ---- Phase 2: reduce over segs, sigmoid, write probs (coalesced) -----
    {
        const int rtok = tid >> 4;
        const int e    = tid & 15;
        float s = 0.f;
#pragma unroll
        for (int sg = 0; sg < 16; sg++) s += red[sg][rtok][e];
        s += gate_b[e];
        if (write_aux) {
            float prob = 1.f / (1.f + expf(-s));
            out_probs[(size_t)(blockIdx.x * TPB + rtok) * NE + e] = prob;
        }
        lgt[rtok * NE + e] = s;
    }
    __syncthreads();

    // ---- Phase 3: top-2 per token (threads 0..15) ------------------------
    if (tid < TPB) {
        const int ftok = tid;
        const int gtoken = blockIdx.x * TPB + ftok;
        float go[NE], logit[NE];
#pragma unroll
        for (int e = 0; e < NE; e++) {
            go[e] = lgt[ftok * NE + e];
            logit[e] = go[e] + ebias[e];
        }
        int i0 = 0;
        for (int e = 1; e < NE; e++) if (logit[e] > logit[i0]) i0 = e;
        int i1 = -1;
        for (int e = 0; e < NE; e++) {
            if (e == i0) continue;
            if (i1 < 0 || logit[e] > logit[i1]) i1 = e;
        }
        float p0 = 1.f / (1.f + expf(-go[i0]));
        float p1 = 1.f / (1.f + expf(-go[i1]));
        float inv = 1.f / (p0 + p1);
        if (write_aux) {
            out_idx[(size_t)gtoken * KK + 0] = (float)i0;
            out_idx[(size_t)gtoken * KK + 1] = (float)i1;
        }
        s_rec[ftok] = make_float4((float)i0, (float)i1, p0 * inv, p1 * inv);
    }
    __syncthreads();

    // ---- Phase 4: expert dots from registers + wc (L2-hot) ---------------
    {
        float4 rec = s_rec[tok];
        int e0 = (int)rec.x;
        int e1 = (int)rec.y;
        const float4* w0 = (const float4*)(wc + ((size_t)e0 * KK + 0) * DIN_) + seg * 16;
        const float4* w1 = (const float4*)(wc + ((size_t)e1 * KK + 1) * DIN_) + seg * 16;
        float g0 = 0.f, g1 = 0.f;
#pragma unroll
        for (int i = 0; i < 16; i++) {
            float4 xv = xr[i];
            float4 a = w0[i];
            float4 b = w1[i];
            g0 += xv.x * a.x + xv.y * a.y + xv.z * a.z + xv.w * a.w;
            g1 += xv.x * b.x + xv.y * b.y + xv.z * b.z + xv.w * b.w;
        }
        red[seg][tok][0] = g0;
        red[seg][tok][1] = g1;
    }
    __syncthreads();

    // ---- Phase 5: finalize scalar per token ------------------------------
    if (tid < TPB) {
        const int ftok = tid;
        float4 rec = s_rec[ftok];
        int e0 = (int)rec.x;
        int e1 = (int)rec.y;
        float g0 = 0.f, g1 = 0.f;
#pragma unroll
        for (int sg = 0; sg < 16; sg++) { g0 += red[sg][ftok][0]; g1 += red[sg][ftok][1]; }
        g0 += expert_b[(size_t)e0 * DOUT_ + 0];
        g1 += expert_b[(size_t)e1 * DOUT_ + 1];
        s_final[ftok] = rec.z * g0 + rec.w * g1;
    }
    __syncthreads();

    // ---- Phase 6: broadcast stores, fully coalesced ----------------------
    // iter k: all 256 threads write token k's row (256 float4 = 4 KB)
    float4* ob = (float4*)(out_final + (size_t)blockIdx.x * TPB * DOUT_);
#pragma unroll
    for (int k = 0; k < TPB; k++) {
        float f = s_final[k];
        ob[k * (DOUT_ / 4) + tid] = make_float4(f, f, f, f);
    }
}

// ---------------------------------------------------------------------------
extern "C" void kernel_launch(void* const* d_in, const int* in_sizes, int n_in,
                              void* d_out, int out_size, void* d_ws, size_t ws_size,
                              hipStream_t stream) {
    const float* x        = (const float*)d_in[0];
    const float* gate_w   = (const float*)d_in[1];
    const float* gate_b   = (const float*)d_in[2];
    const float* expert_w = (const float*)d_in[3];
    const float* expert_b = (const float*)d_in[4];
    const float* ebias    = (const float*)d_in[5];
    float* out = (float*)d_out;

    float* wc = (float*)d_ws;   // 128 KB compact expert columns

    float* out_final = out;
    float* out_probs = out + (size_t)NTOK * DOUT_;
    float* out_idx   = out_probs + (size_t)NTOK * NE;
    int write_aux = (out_size >= NTOK * DOUT_ + NTOK * NE + NTOK * KK) ? 1 : 0;

    compact_w_kernel<<<(NE * KK * DIN_ + 255) / 256, 256, 0, stream>>>(expert_w, wc);
    moe_fused_kernel<<<NTOK / TPB, 256, 0, stream>>>(
        x, gate_w, gate_b, ebias, wc, expert_b,
        out_final, out_probs, out_idx, write_aux);
}